// Round 1
// baseline (320.569 us; speedup 1.0000x reference)
//
#include <hip/hip_runtime.h>
#include <stdint.h>

typedef short short8 __attribute__((ext_vector_type(8)));
typedef float f32x4 __attribute__((ext_vector_type(4)));

#define TILE 128          // A-tile rows per block (and K_MM reg-tile rows)
#define BCOLS 64          // B-tile cols per m-iteration (was 128; halves LDS dbuf)

__device__ __forceinline__ unsigned short f32_to_bf16(float f) {
    uint32_t u = __builtin_bit_cast(uint32_t, f);
    u += 0x7FFFu + ((u >> 16) & 1u);   // RNE; data has no NaNs
    return (unsigned short)(u >> 16);
}
__device__ __forceinline__ float bf16_to_f32(unsigned short h) {
    return __builtin_bit_cast(float, (uint32_t)h << 16);
}

// async global->LDS DMA, 16 B per lane per issue (global_load_lds_dwordx4).
// HW semantics: per-lane global address; LDS dest = wave-uniform base + lane*16.
typedef const __attribute__((address_space(1))) uint32_t guint;
typedef __attribute__((address_space(3))) uint32_t luint;
__device__ __forceinline__ void dma16(const void* g, void* l) {
    __builtin_amdgcn_global_load_lds((guint*)g, (luint*)l, 16, 0, 0);
}

// Prep: centers fp32 -> bf16 in MFMA fragment layout, cw[m] = {||c||^2 * q, alpha[m]},
// and zero the accumulators (loss, reg, block counter).
// Fragment layout: element (row R, k) -> Bp[(R/16)*2048 + (k/8)*128 + (R%16)*8 + (k%8)]
__global__ void prep_kernel(const float* __restrict__ C,
                            const float* __restrict__ alpha,
                            const float* __restrict__ sigma,
                            unsigned short* __restrict__ Bp,
                            float2* __restrict__ cw,
                            float* __restrict__ acc)
{
    const int t = threadIdx.x;
    const int g = blockIdx.x;          // 16-row group
    const int r = t >> 4;              // row within group
    const int c16 = t & 15;            // 8-elem k-chunk
    const int R = g * 16 + r;

    if (g == 0 && t == 0) {
        acc[0] = 0.f; acc[1] = 0.f;
        ((unsigned int*)acc)[2] = 0u;
    }

    const float4* src = (const float4*)(C + (size_t)R * 128 + c16 * 8);
    float4 va = src[0], vb = src[1];
    unsigned short h[8];
    h[0] = f32_to_bf16(va.x); h[1] = f32_to_bf16(va.y);
    h[2] = f32_to_bf16(va.z); h[3] = f32_to_bf16(va.w);
    h[4] = f32_to_bf16(vb.x); h[5] = f32_to_bf16(vb.y);
    h[6] = f32_to_bf16(vb.z); h[7] = f32_to_bf16(vb.w);
    float ss = 0.f;
    #pragma unroll
    for (int k = 0; k < 8; ++k) {
        float f = bf16_to_f32(h[k]);
        ss = fmaf(f, f, ss);
    }
    uint4 pk;
    pk.x = (uint32_t)h[0] | ((uint32_t)h[1] << 16);
    pk.y = (uint32_t)h[2] | ((uint32_t)h[3] << 16);
    pk.z = (uint32_t)h[4] | ((uint32_t)h[5] << 16);
    pk.w = (uint32_t)h[6] | ((uint32_t)h[7] << 16);
    *reinterpret_cast<uint4*>(Bp + (size_t)g * 2048 + c16 * 128 + r * 8) = pk;

    ss += __shfl_xor(ss, 1);
    ss += __shfl_xor(ss, 2);
    ss += __shfl_xor(ss, 4);
    ss += __shfl_xor(ss, 8);
    if (c16 == 0) {
        float sig = sigma[0];
        float q = 0.7213475204444817f / (sig * sig);  // log2(e)/(2 sigma^2)
        cw[R] = make_float2(ss * q, alpha[R]);
    }
}

// Fused: blocks [0,nA) = preds + loss-sum; blocks [nA,nA+nMt) = K_MM regularizer.
// 512 threads = 8 waves in a 4(row)x2(col) grid; each wave owns 32 rows x 32
// cols of the 128x64 tile.
//
// R8 change vs the 182us version: B tiles narrowed 128->64 cols, so the LDS
// double buffer shrinks 2x32KB -> 2x16KB and total LDS drops 67KB -> 35KB.
// Rocprof showed the old kernel was stall-bound (MfmaUtil 19%, VALUBusy 32%,
// Occupancy 30%): VGPR=60 would have allowed 8 waves/SIMD but LDS=67KB capped
// residency at 2 blocks/CU, and 798 blocks over 512 slots ran in 1.56 rounds.
// At 35KB + __launch_bounds__(512,8) (VGPR cap 64, currently 60) we get
// 4 blocks/CU = 32 waves/CU and the whole grid is co-resident in one round;
// barrier/DMA stalls of one block are hidden by the other three.
// Amplification, DMA traffic, fragment layout, and register pressure are
// unchanged (cj shrinks 4->2). Barriers double (32/tile-loop) but overlap.
__global__ __launch_bounds__(512, 8)
void fused_kernel(const float* __restrict__ X, int N,
                  const float* __restrict__ Yv,
                  const unsigned short* __restrict__ Bp,
                  const float2* __restrict__ cw,
                  const float* __restrict__ alpha,
                  const float* __restrict__ sigma,
                  const float* __restrict__ penalty,
                  int nA, int nMt, int nBlk,
                  float* __restrict__ preds_out,
                  float* __restrict__ out0,
                  float* __restrict__ acc)   // [0]=loss,[1]=reg,[2]=counter
{
    // ldsB (both halves, 32KB contiguous) doubles as the A-staging buffer
    // before the m-loop starts.
    __shared__ __align__(16) unsigned short ldsB[2][8192];  // 2 x 16 KB
    __shared__ float a2p[TILE][4];
    __shared__ float predbuf[TILE][2];

    const int t    = threadIdx.x;
    const int lane = t & 63;
    const int wid  = t >> 6;     // 0..7
    const int wr   = wid >> 1;   // 0..3: rows wr*32 .. +32
    const int wc   = wid & 1;    // 0..1: cols wc*32 .. +32
    const int l15  = lane & 15;
    const int quad = lane >> 4;

    const float sig = sigma[0];
    const float q  = 0.7213475204444817f / (sig * sig);
    const float q2 = 2.0f * q;

    const bool regmode = (int)blockIdx.x >= nA;
    int rowbase;
    float rowterm[2][4];
    short8 a[8];   // A fragments, tile-invariant: a[i*4+kk], i in {0,1}

    if (!regmode) {
        rowbase = blockIdx.x * TILE;
        // stage X tile into fragment-layout LDS (whole 32KB of ldsB);
        // each thread converts a quarter-row (32 elems)
        const int r_  = t >> 2;
        const int qtr = t & 3;
        const int grow = rowbase + r_;
        unsigned short* dstbase = &ldsB[0][0] + (r_ >> 4) * 2048 + (r_ & 15) * 8;
        float ss = 0.f;
        if (grow < N) {
            const float4* src = (const float4*)(X + (size_t)grow * 128 + qtr * 32);
            #pragma unroll
            for (int c = 0; c < 4; ++c) {
                float4 va = src[2 * c], vb = src[2 * c + 1];
                unsigned short h0 = f32_to_bf16(va.x), h1 = f32_to_bf16(va.y);
                unsigned short h2 = f32_to_bf16(va.z), h3 = f32_to_bf16(va.w);
                unsigned short h4 = f32_to_bf16(vb.x), h5 = f32_to_bf16(vb.y);
                unsigned short h6 = f32_to_bf16(vb.z), h7 = f32_to_bf16(vb.w);
                float f0 = bf16_to_f32(h0), f1 = bf16_to_f32(h1);
                float f2 = bf16_to_f32(h2), f3 = bf16_to_f32(h3);
                float f4 = bf16_to_f32(h4), f5 = bf16_to_f32(h5);
                float f6 = bf16_to_f32(h6), f7 = bf16_to_f32(h7);
                ss = fmaf(f0, f0, ss); ss = fmaf(f1, f1, ss);
                ss = fmaf(f2, f2, ss); ss = fmaf(f3, f3, ss);
                ss = fmaf(f4, f4, ss); ss = fmaf(f5, f5, ss);
                ss = fmaf(f6, f6, ss); ss = fmaf(f7, f7, ss);
                uint4 pk;
                pk.x = (uint32_t)h0 | ((uint32_t)h1 << 16);
                pk.y = (uint32_t)h2 | ((uint32_t)h3 << 16);
                pk.z = (uint32_t)h4 | ((uint32_t)h5 << 16);
                pk.w = (uint32_t)h6 | ((uint32_t)h7 << 16);
                *reinterpret_cast<uint4*>(dstbase + (qtr * 4 + c) * 128) = pk;
            }
        } else {
            uint4 z; z.x = z.y = z.z = z.w = 0u;
            #pragma unroll
            for (int c = 0; c < 4; ++c)
                *reinterpret_cast<uint4*>(dstbase + (qtr * 4 + c) * 128) = z;
        }
        a2p[r_][qtr] = ss;
        __syncthreads();
        #pragma unroll
        for (int i = 0; i < 2; ++i)
            #pragma unroll
            for (int r = 0; r < 4; ++r) {
                int rl = wr * 32 + i * 16 + quad * 4 + r;
                rowterm[i][r] = (a2p[rl][0] + a2p[rl][1] + a2p[rl][2] + a2p[rl][3]) * q;
            }
        // hoist A fragments: 8 ds_read_b128, once for the whole kernel
        const unsigned short* aLds = &ldsB[0][0] + (size_t)(wr * 2) * 2048 + lane * 8;
        #pragma unroll
        for (int i = 0; i < 2; ++i)
            #pragma unroll
            for (int kk = 0; kk < 4; ++kk)
                a[i * 4 + kk] = *reinterpret_cast<const short8*>(aLds + (size_t)i * 2048 + kk * 512);
        __syncthreads();   // all waves done reading A from ldsB before DMA overwrites
    } else {
        const int b2 = (int)blockIdx.x - nA;
        rowbase = b2 * TILE;
        const unsigned short* aG = Bp + (size_t)(b2 * 8 + wr * 2) * 2048 + lane * 8;
        #pragma unroll
        for (int i = 0; i < 2; ++i)
            #pragma unroll
            for (int kk = 0; kk < 4; ++kk)
                a[i * 4 + kk] = *reinterpret_cast<const short8*>(aG + (size_t)i * 2048 + kk * 512);
        #pragma unroll
        for (int i = 0; i < 2; ++i)
            #pragma unroll
            for (int r = 0; r < 4; ++r)
                rowterm[i][r] = cw[rowbase + wr * 32 + i * 16 + quad * 4 + r].x;
    }

    float srow[2][4] = {};
    const float2* cwb = cw + wc * 32 + l15;

    // this wave stages its 2 KB eighth of each 16KB tile: 2 x 1KB DMA issues
    const int ldq = wid * 1024 + lane * 8;   // element offset (shorts)

    // DMA tile 0 into ldsB[0]
    {
        const unsigned short* g = Bp + ldq;
        unsigned short* l = &ldsB[0][0] + ldq;
        #pragma unroll
        for (int k = 0; k < 2; ++k)
            dma16(g + k * 512, l + k * 512);
    }
    __syncthreads();   // vmcnt drain: tile 0 resident

    for (int mt = 0; mt < nMt; ++mt) {
        if (mt + 1 < nMt) {
            // fire-and-forget DMA of tile mt+1 into the other buffer;
            // drained by the barrier at the END of this iteration.
            const unsigned short* g = Bp + (size_t)(mt + 1) * 8192 + ldq;
            unsigned short* l = &ldsB[(mt + 1) & 1][0] + ldq;
            #pragma unroll
            for (int k = 0; k < 2; ++k)
                dma16(g + k * 512, l + k * 512);
        }

        // column constants for this tile (L2-hot; latency covered by TLP)
        float2 cj[2];
        #pragma unroll
        for (int j = 0; j < 2; ++j) cj[j] = cwb[(size_t)mt * 64 + j * 16];

        // compute tile mt from LDS: 2 column groups of 16, K=128 each
        const unsigned short* bfr = &ldsB[mt & 1][0] + (size_t)(wc * 2) * 2048 + lane * 8;
        #pragma unroll
        for (int j = 0; j < 2; ++j) {
            short8 b[4];
            #pragma unroll
            for (int kk = 0; kk < 4; ++kk)
                b[kk] = *reinterpret_cast<const short8*>(bfr + (size_t)j * 2048 + kk * 512);

            f32x4 acc4[2];
            #pragma unroll
            for (int i = 0; i < 2; ++i) acc4[i] = (f32x4){0.f, 0.f, 0.f, 0.f};
            #pragma unroll
            for (int kk = 0; kk < 4; ++kk)
                #pragma unroll
                for (int i = 0; i < 2; ++i)
                    acc4[i] = __builtin_amdgcn_mfma_f32_16x16x32_bf16(
                        a[i * 4 + kk], b[kk], acc4[i], 0, 0, 0);

            // epilogue: u = 2q*dot - (q*x2 + q*c2) <= ~0 ; srow += exp2(u)*alpha
            #pragma unroll
            for (int i = 0; i < 2; ++i) {
                #pragma unroll
                for (int r = 0; r < 4; ++r) {
                    float u = fmaf(acc4[i][r], q2, -(rowterm[i][r] + cj[j].x));
                    float e = __builtin_amdgcn_exp2f(u);
                    srow[i][r] = fmaf(e, cj[j].y, srow[i][r]);
                }
            }
        }

        __syncthreads();   // drains DMA(mt+1); all waves done reading buf[mt&1]
    }

    // reduce srow over the 16 lanes sharing a row
    #pragma unroll
    for (int i = 0; i < 2; ++i) {
        #pragma unroll
        for (int r = 0; r < 4; ++r) {
            int rl = wr * 32 + i * 16 + quad * 4 + r;
            float v = srow[i][r];
            v += __shfl_xor(v, 1);
            v += __shfl_xor(v, 2);
            v += __shfl_xor(v, 4);
            v += __shfl_xor(v, 8);
            if (l15 == 0)
                predbuf[rl][wc] = v;
        }
    }
    __syncthreads();

    float contrib = 0.f;
    if (t < TILE) {
        int grow = rowbase + t;
        if (!regmode) {
            if (grow < N) {
                float pred = predbuf[t][0] + predbuf[t][1];
                preds_out[grow] = pred;
                float d = pred - Yv[grow];
                contrib = d * d;
            }
        } else {
            float pred = predbuf[t][0] + predbuf[t][1];
            contrib = alpha[grow] * pred;
        }
    }
    contrib += __shfl_xor(contrib, 1);
    contrib += __shfl_xor(contrib, 2);
    contrib += __shfl_xor(contrib, 4);
    contrib += __shfl_xor(contrib, 8);
    contrib += __shfl_xor(contrib, 16);
    contrib += __shfl_xor(contrib, 32);
    if (lane == 0 && wid < 2) atomicAdd(regmode ? (acc + 1) : (acc + 0), contrib);

    __syncthreads();   // all waves' atomics drained before counting
    if (t == 0) {
        __threadfence();
        unsigned int old = atomicAdd((unsigned int*)(acc + 2), 1u);
        if (old == (unsigned int)(nBlk - 1)) {
            float lv = atomicAdd(acc + 0, 0.0f);   // coherent read-back
            float rv = atomicAdd(acc + 1, 0.0f);
            out0[0] = lv / (float)N + __expf(-penalty[0]) * rv;
        }
    }
}

extern "C" void kernel_launch(void* const* d_in, const int* in_sizes, int n_in,
                              void* d_out, int out_size, void* d_ws, size_t ws_size,
                              hipStream_t stream) {
    const float* X       = (const float*)d_in[0];
    const float* Y       = (const float*)d_in[1];
    const float* centers = (const float*)d_in[2];
    const float* alpha   = (const float*)d_in[3];
    const float* sigma   = (const float*)d_in[4];
    const float* penalty = (const float*)d_in[5];
    float* out = (float*)d_out;

    const int N = in_sizes[1];   // Y is [N,1]
    const int M = in_sizes[3];   // alpha is [M,1]

    unsigned short* Bp = (unsigned short*)d_ws;                 // M*128 bf16 = M*256 B
    float2* cw = (float2*)((char*)d_ws + (size_t)M * 256);      // M*8 B
    float* acc = (float*)((char*)d_ws + (size_t)M * 264);       // loss, reg, counter

    prep_kernel<<<M / 16, 256, 0, stream>>>(centers, alpha, sigma, Bp, cw, acc);

    const int nA  = (N + TILE - 1) / TILE;
    const int nMt = M / BCOLS;            // 64-col B tiles
    const int nBlk = nA + M / TILE;
    fused_kernel<<<nBlk, 512, 0, stream>>>(X, N, Y, Bp, cw, alpha, sigma, penalty,
                                           nA, nMt, nBlk, out + 1, out, acc);
}

// Round 2
// 201.866 us; speedup vs baseline: 1.5880x; 1.5880x over previous
//
#include <hip/hip_runtime.h>
#include <stdint.h>

typedef short short8 __attribute__((ext_vector_type(8)));
typedef float f32x4 __attribute__((ext_vector_type(4)));

#define TILE 128          // A-tile rows per block (and K_MM reg-tile rows)
#define BCOLS 32          // B-tile cols per m-iteration (8 KB tiles, quad-buffered)

__device__ __forceinline__ unsigned short f32_to_bf16(float f) {
    uint32_t u = __builtin_bit_cast(uint32_t, f);
    u += 0x7FFFu + ((u >> 16) & 1u);   // RNE; data has no NaNs
    return (unsigned short)(u >> 16);
}
__device__ __forceinline__ float bf16_to_f32(unsigned short h) {
    return __builtin_bit_cast(float, (uint32_t)h << 16);
}

// async global->LDS DMA, 16 B per lane per issue (global_load_lds_dwordx4).
// HW semantics: per-lane global address; LDS dest = wave-uniform base + lane*16
// (for ACTIVE lanes; exec-masked lanes transfer nothing).
typedef const __attribute__((address_space(1))) uint32_t guint;
typedef __attribute__((address_space(3))) uint32_t luint;
__device__ __forceinline__ void dma16(const void* g, void* l) {
    __builtin_amdgcn_global_load_lds((guint*)g, (luint*)l, 16, 0, 0);
}

// Prep: centers fp32 -> bf16 in MFMA fragment layout, cw[m] = {||c||^2 * q, alpha[m]},
// and zero the accumulators (loss, reg, block counter).
// Fragment layout: element (row R, k) -> Bp[(R/16)*2048 + (k/8)*128 + (R%16)*8 + (k%8)]
__global__ void prep_kernel(const float* __restrict__ C,
                            const float* __restrict__ alpha,
                            const float* __restrict__ sigma,
                            unsigned short* __restrict__ Bp,
                            float2* __restrict__ cw,
                            float* __restrict__ acc)
{
    const int t = threadIdx.x;
    const int g = blockIdx.x;          // 16-row group
    const int r = t >> 4;              // row within group
    const int c16 = t & 15;            // 8-elem k-chunk
    const int R = g * 16 + r;

    if (g == 0 && t == 0) {
        acc[0] = 0.f; acc[1] = 0.f;
        ((unsigned int*)acc)[2] = 0u;
    }

    const float4* src = (const float4*)(C + (size_t)R * 128 + c16 * 8);
    float4 va = src[0], vb = src[1];
    unsigned short h[8];
    h[0] = f32_to_bf16(va.x); h[1] = f32_to_bf16(va.y);
    h[2] = f32_to_bf16(va.z); h[3] = f32_to_bf16(va.w);
    h[4] = f32_to_bf16(vb.x); h[5] = f32_to_bf16(vb.y);
    h[6] = f32_to_bf16(vb.z); h[7] = f32_to_bf16(vb.w);
    float ss = 0.f;
    #pragma unroll
    for (int k = 0; k < 8; ++k) {
        float f = bf16_to_f32(h[k]);
        ss = fmaf(f, f, ss);
    }
    uint4 pk;
    pk.x = (uint32_t)h[0] | ((uint32_t)h[1] << 16);
    pk.y = (uint32_t)h[2] | ((uint32_t)h[3] << 16);
    pk.z = (uint32_t)h[4] | ((uint32_t)h[5] << 16);
    pk.w = (uint32_t)h[6] | ((uint32_t)h[7] << 16);
    *reinterpret_cast<uint4*>(Bp + (size_t)g * 2048 + c16 * 128 + r * 8) = pk;

    ss += __shfl_xor(ss, 1);
    ss += __shfl_xor(ss, 2);
    ss += __shfl_xor(ss, 4);
    ss += __shfl_xor(ss, 8);
    if (c16 == 0) {
        float sig = sigma[0];
        float q = 0.7213475204444817f / (sig * sig);  // log2(e)/(2 sigma^2)
        cw[R] = make_float2(ss * q, alpha[R]);
    }
}

// Fused: blocks [0,nA) = preds + loss-sum; blocks [nA,nA+nMt) = K_MM regularizer.
// 512 threads = 8 waves in a 4(row)x2(col) grid; each wave owns 32 rows x 16
// cols of the 128x32 tile.
//
// R3 change: depth-3 software pipeline (T3/T4). The R2 kernel's per-iteration
// __syncthreads() drains vmcnt(0), giving the next tile's DMA only ~1 compute
// iteration of latency cover and convoying all 8 waves into lockstep phases
// (MfmaUtil 28 / VALUBusy 49 both half-duty). Now: 4 x 8KB B buffers, DMA
// issued 3 tiles ahead, counted `s_waitcnt vmcnt(4)` + raw s_barrier per iter
// (never vmcnt(0) until the 2-iter peeled tail). Per-tile column constants
// (cw) are DMA'd into LDS next to the B tile -- a register-bound global load
// in the loop would force the compiler to emit a draining waitcnt and kill
// the pipeline depth. LDS = 32K(B) + 2K(a2p) + 1K(pred) + 1K(cw) = 36.9 KB
// -> still 4 blocks/CU (3 blocks = 768 slots < 798 grid = straggler cliff).
// Occupancy ledger (R1 lesson): gfx950 unified VGPR+AGPR file; keep
// __launch_bounds__(512,4) -- compiler emits ~60 regs which already fits the
// 8-waves/SIMD (<=64) budget; forcing (512,8) split the file and spilled.
__global__ __launch_bounds__(512, 4)
void fused_kernel(const float* __restrict__ X, int N,
                  const float* __restrict__ Yv,
                  const unsigned short* __restrict__ Bp,
                  const float2* __restrict__ cw,
                  const float* __restrict__ alpha,
                  const float* __restrict__ sigma,
                  const float* __restrict__ penalty,
                  int nA, int nMt, int nBlk,
                  float* __restrict__ preds_out,
                  float* __restrict__ out0,
                  float* __restrict__ acc)   // [0]=loss,[1]=reg,[2]=counter
{
    // ldsB (all four 8KB buffers, 32KB contiguous) doubles as the A-staging
    // buffer before the m-loop starts.
    __shared__ __align__(16) unsigned short ldsB[4][4096];  // 4 x 8 KB
    __shared__ __align__(16) float2 cwLds[4][32];           // per-tile col consts
    __shared__ float a2p[TILE][4];
    __shared__ float predbuf[TILE][2];

    const int t    = threadIdx.x;
    const int lane = t & 63;
    const int wid  = t >> 6;     // 0..7
    const int wr   = wid >> 1;   // 0..3: rows wr*32 .. +32
    const int wc   = wid & 1;    // 0..1: cols wc*16 .. +16 within the 32-col tile
    const int l15  = lane & 15;
    const int quad = lane >> 4;

    const float sig = sigma[0];
    const float q  = 0.7213475204444817f / (sig * sig);
    const float q2 = 2.0f * q;

    const bool regmode = (int)blockIdx.x >= nA;
    int rowbase;
    float rowterm[2][4];
    short8 a[8];   // A fragments, tile-invariant: a[i*4+kk], i in {0,1}

    if (!regmode) {
        rowbase = blockIdx.x * TILE;
        // stage X tile into fragment-layout LDS (whole 32KB of ldsB);
        // each thread converts a quarter-row (32 elems)
        const int r_  = t >> 2;
        const int qtr = t & 3;
        const int grow = rowbase + r_;
        unsigned short* dstbase = &ldsB[0][0] + (r_ >> 4) * 2048 + (r_ & 15) * 8;
        float ss = 0.f;
        if (grow < N) {
            const float4* src = (const float4*)(X + (size_t)grow * 128 + qtr * 32);
            #pragma unroll
            for (int c = 0; c < 4; ++c) {
                float4 va = src[2 * c], vb = src[2 * c + 1];
                unsigned short h0 = f32_to_bf16(va.x), h1 = f32_to_bf16(va.y);
                unsigned short h2 = f32_to_bf16(va.z), h3 = f32_to_bf16(va.w);
                unsigned short h4 = f32_to_bf16(vb.x), h5 = f32_to_bf16(vb.y);
                unsigned short h6 = f32_to_bf16(vb.z), h7 = f32_to_bf16(vb.w);
                float f0 = bf16_to_f32(h0), f1 = bf16_to_f32(h1);
                float f2 = bf16_to_f32(h2), f3 = bf16_to_f32(h3);
                float f4 = bf16_to_f32(h4), f5 = bf16_to_f32(h5);
                float f6 = bf16_to_f32(h6), f7 = bf16_to_f32(h7);
                ss = fmaf(f0, f0, ss); ss = fmaf(f1, f1, ss);
                ss = fmaf(f2, f2, ss); ss = fmaf(f3, f3, ss);
                ss = fmaf(f4, f4, ss); ss = fmaf(f5, f5, ss);
                ss = fmaf(f6, f6, ss); ss = fmaf(f7, f7, ss);
                uint4 pk;
                pk.x = (uint32_t)h0 | ((uint32_t)h1 << 16);
                pk.y = (uint32_t)h2 | ((uint32_t)h3 << 16);
                pk.z = (uint32_t)h4 | ((uint32_t)h5 << 16);
                pk.w = (uint32_t)h6 | ((uint32_t)h7 << 16);
                *reinterpret_cast<uint4*>(dstbase + (qtr * 4 + c) * 128) = pk;
            }
        } else {
            uint4 z; z.x = z.y = z.z = z.w = 0u;
            #pragma unroll
            for (int c = 0; c < 4; ++c)
                *reinterpret_cast<uint4*>(dstbase + (qtr * 4 + c) * 128) = z;
        }
        a2p[r_][qtr] = ss;
        __syncthreads();
        #pragma unroll
        for (int i = 0; i < 2; ++i)
            #pragma unroll
            for (int r = 0; r < 4; ++r) {
                int rl = wr * 32 + i * 16 + quad * 4 + r;
                rowterm[i][r] = (a2p[rl][0] + a2p[rl][1] + a2p[rl][2] + a2p[rl][3]) * q;
            }
        // hoist A fragments: 8 ds_read_b128, once for the whole kernel
        const unsigned short* aLds = &ldsB[0][0] + (size_t)(wr * 2) * 2048 + lane * 8;
        #pragma unroll
        for (int i = 0; i < 2; ++i)
            #pragma unroll
            for (int kk = 0; kk < 4; ++kk)
                a[i * 4 + kk] = *reinterpret_cast<const short8*>(aLds + (size_t)i * 2048 + kk * 512);
        __syncthreads();   // all waves done reading A from ldsB before DMA overwrites
    } else {
        const int b2 = (int)blockIdx.x - nA;
        rowbase = b2 * TILE;
        const unsigned short* aG = Bp + (size_t)(b2 * 8 + wr * 2) * 2048 + lane * 8;
        #pragma unroll
        for (int i = 0; i < 2; ++i)
            #pragma unroll
            for (int kk = 0; kk < 4; ++kk)
                a[i * 4 + kk] = *reinterpret_cast<const short8*>(aG + (size_t)i * 2048 + kk * 512);
        #pragma unroll
        for (int i = 0; i < 2; ++i)
            #pragma unroll
            for (int r = 0; r < 4; ++r)
                rowterm[i][r] = cw[rowbase + wr * 32 + i * 16 + quad * 4 + r].x;
    }

    float srow[2][4] = {};

    // Each tile = 8 KB = 512 threads x 16 B: one dma16 per thread.
    const int ldq = t * 8;   // element offset (shorts); byte offset = t*16

    // prologue: stage tiles 0,1,2 (2 vmem ops per tile per wave: B + cw)
    #pragma unroll
    for (int p = 0; p < 3; ++p) {
        dma16(Bp + (size_t)p * 4096 + ldq, &ldsB[p][0] + ldq);
        if (lane < 16)
            dma16(cw + (size_t)p * BCOLS + (lane << 1), &cwLds[p][lane << 1]);
    }

    // Per-iteration: wait for tile MT (2 ops per in-flight tile ahead of it),
    // barrier (everyone past compute MT-1, so buf (MT+3)&3 is reusable),
    // issue DMA for MT+3, compute MT. vmcnt FIFO per wave: only dma16 ops.
#define MITER(MT, VM)                                                         \
    do {                                                                      \
        asm volatile("s_waitcnt vmcnt(" #VM ")");                             \
        __builtin_amdgcn_sched_barrier(0);                                    \
        __builtin_amdgcn_s_barrier();                                         \
        __builtin_amdgcn_sched_barrier(0);                                    \
        const int nxt_ = (MT) + 3;                                            \
        if (nxt_ < nMt) {                                                     \
            dma16(Bp + (size_t)nxt_ * 4096 + ldq, &ldsB[nxt_ & 3][0] + ldq);  \
            if (lane < 16)                                                    \
                dma16(cw + (size_t)nxt_ * BCOLS + (lane << 1),                \
                      &cwLds[nxt_ & 3][lane << 1]);                           \
        }                                                                     \
        const int cb_ = (MT) & 3;                                             \
        float2 cj = cwLds[cb_][wc * 16 + l15];                                \
        const unsigned short* bfr = &ldsB[cb_][0] + wc * 2048 + lane * 8;     \
        short8 b0 = *reinterpret_cast<const short8*>(bfr);                    \
        short8 b1 = *reinterpret_cast<const short8*>(bfr + 512);              \
        short8 b2 = *reinterpret_cast<const short8*>(bfr + 1024);             \
        short8 b3 = *reinterpret_cast<const short8*>(bfr + 1536);             \
        f32x4 acc0 = (f32x4){0.f, 0.f, 0.f, 0.f};                             \
        f32x4 acc1 = (f32x4){0.f, 0.f, 0.f, 0.f};                             \
        acc0 = __builtin_amdgcn_mfma_f32_16x16x32_bf16(a[0], b0, acc0, 0, 0, 0); \
        acc1 = __builtin_amdgcn_mfma_f32_16x16x32_bf16(a[4], b0, acc1, 0, 0, 0); \
        acc0 = __builtin_amdgcn_mfma_f32_16x16x32_bf16(a[1], b1, acc0, 0, 0, 0); \
        acc1 = __builtin_amdgcn_mfma_f32_16x16x32_bf16(a[5], b1, acc1, 0, 0, 0); \
        acc0 = __builtin_amdgcn_mfma_f32_16x16x32_bf16(a[2], b2, acc0, 0, 0, 0); \
        acc1 = __builtin_amdgcn_mfma_f32_16x16x32_bf16(a[6], b2, acc1, 0, 0, 0); \
        acc0 = __builtin_amdgcn_mfma_f32_16x16x32_bf16(a[3], b3, acc0, 0, 0, 0); \
        acc1 = __builtin_amdgcn_mfma_f32_16x16x32_bf16(a[7], b3, acc1, 0, 0, 0); \
        _Pragma("unroll")                                                     \
        for (int r = 0; r < 4; ++r) {                                         \
            float u0 = fmaf(acc0[r], q2, -(rowterm[0][r] + cj.x));            \
            float u1 = fmaf(acc1[r], q2, -(rowterm[1][r] + cj.x));            \
            srow[0][r] = fmaf(__builtin_amdgcn_exp2f(u0), cj.y, srow[0][r]);  \
            srow[1][r] = fmaf(__builtin_amdgcn_exp2f(u1), cj.y, srow[1][r]);  \
        }                                                                     \
    } while (0)

    for (int mt = 0; mt < nMt - 2; ++mt)
        MITER(mt, 4);           // tiles mt+1, mt+2 in flight (2 ops each)
    MITER(nMt - 2, 2);          // only tile nMt-1 in flight
    MITER(nMt - 1, 0);          // nothing in flight
#undef MITER

    // reduce srow over the 16 lanes sharing a row
    #pragma unroll
    for (int i = 0; i < 2; ++i) {
        #pragma unroll
        for (int r = 0; r < 4; ++r) {
            int rl = wr * 32 + i * 16 + quad * 4 + r;
            float v = srow[i][r];
            v += __shfl_xor(v, 1);
            v += __shfl_xor(v, 2);
            v += __shfl_xor(v, 4);
            v += __shfl_xor(v, 8);
            if (l15 == 0)
                predbuf[rl][wc] = v;
        }
    }
    __syncthreads();

    float contrib = 0.f;
    if (t < TILE) {
        int grow = rowbase + t;
        if (!regmode) {
            if (grow < N) {
                float pred = predbuf[t][0] + predbuf[t][1];
                preds_out[grow] = pred;
                float d = pred - Yv[grow];
                contrib = d * d;
            }
        } else {
            float pred = predbuf[t][0] + predbuf[t][1];
            contrib = alpha[grow] * pred;
        }
    }
    contrib += __shfl_xor(contrib, 1);
    contrib += __shfl_xor(contrib, 2);
    contrib += __shfl_xor(contrib, 4);
    contrib += __shfl_xor(contrib, 8);
    contrib += __shfl_xor(contrib, 16);
    contrib += __shfl_xor(contrib, 32);
    if (lane == 0 && wid < 2) atomicAdd(regmode ? (acc + 1) : (acc + 0), contrib);

    __syncthreads();   // all waves' atomics drained before counting
    if (t == 0) {
        __threadfence();
        unsigned int old = atomicAdd((unsigned int*)(acc + 2), 1u);
        if (old == (unsigned int)(nBlk - 1)) {
            float lv = atomicAdd(acc + 0, 0.0f);   // coherent read-back
            float rv = atomicAdd(acc + 1, 0.0f);
            out0[0] = lv / (float)N + __expf(-penalty[0]) * rv;
        }
    }
}

extern "C" void kernel_launch(void* const* d_in, const int* in_sizes, int n_in,
                              void* d_out, int out_size, void* d_ws, size_t ws_size,
                              hipStream_t stream) {
    const float* X       = (const float*)d_in[0];
    const float* Y       = (const float*)d_in[1];
    const float* centers = (const float*)d_in[2];
    const float* alpha   = (const float*)d_in[3];
    const float* sigma   = (const float*)d_in[4];
    const float* penalty = (const float*)d_in[5];
    float* out = (float*)d_out;

    const int N = in_sizes[1];   // Y is [N,1]
    const int M = in_sizes[3];   // alpha is [M,1]

    unsigned short* Bp = (unsigned short*)d_ws;                 // M*128 bf16 = M*256 B
    float2* cw = (float2*)((char*)d_ws + (size_t)M * 256);      // M*8 B
    float* acc = (float*)((char*)d_ws + (size_t)M * 264);       // loss, reg, counter

    prep_kernel<<<M / 16, 256, 0, stream>>>(centers, alpha, sigma, Bp, cw, acc);

    const int nA  = (N + TILE - 1) / TILE;
    const int nMt = M / BCOLS;            // 32-col B tiles
    const int nBlk = nA + M / TILE;
    fused_kernel<<<nBlk, 512, 0, stream>>>(X, N, Y, Bp, cw, alpha, sigma, penalty,
                                           nA, nMt, nBlk, out + 1, out, acc);
}

// Round 3
// 175.453 us; speedup vs baseline: 1.8271x; 1.1505x over previous
//
#include <hip/hip_runtime.h>
#include <stdint.h>

typedef short short8 __attribute__((ext_vector_type(8)));
typedef float f32x4 __attribute__((ext_vector_type(4)));

#define TILE 128          // A-tile rows per block (and K_MM reg-tile rows)
#define BCOLS 64          // B-tile cols per m-iteration

__device__ __forceinline__ unsigned short f32_to_bf16(float f) {
    uint32_t u = __builtin_bit_cast(uint32_t, f);
    u += 0x7FFFu + ((u >> 16) & 1u);   // RNE; data has no NaNs
    return (unsigned short)(u >> 16);
}
__device__ __forceinline__ float bf16_to_f32(unsigned short h) {
    return __builtin_bit_cast(float, (uint32_t)h << 16);
}

// async global->LDS DMA, 16 B per lane per issue (global_load_lds_dwordx4).
// HW semantics: per-lane global address; LDS dest = wave-uniform base + lane*16.
typedef const __attribute__((address_space(1))) uint32_t guint;
typedef __attribute__((address_space(3))) uint32_t luint;
__device__ __forceinline__ void dma16(const void* g, void* l) {
    __builtin_amdgcn_global_load_lds((guint*)g, (luint*)l, 16, 0, 0);
}

// Prep: centers fp32 -> bf16 in MFMA fragment layout, cw[m] = {||c||^2 * q, alpha[m]},
// and zero the accumulators (loss, reg, block counter).
// Fragment layout: element (row R, k) -> Bp[(R/16)*2048 + (k/8)*128 + (R%16)*8 + (k%8)]
__global__ void prep_kernel(const float* __restrict__ C,
                            const float* __restrict__ alpha,
                            const float* __restrict__ sigma,
                            unsigned short* __restrict__ Bp,
                            float2* __restrict__ cw,
                            float* __restrict__ acc)
{
    const int t = threadIdx.x;
    const int g = blockIdx.x;          // 16-row group
    const int r = t >> 4;              // row within group
    const int c16 = t & 15;            // 8-elem k-chunk
    const int R = g * 16 + r;

    if (g == 0 && t == 0) {
        acc[0] = 0.f; acc[1] = 0.f;
        ((unsigned int*)acc)[2] = 0u;
    }

    const float4* src = (const float4*)(C + (size_t)R * 128 + c16 * 8);
    float4 va = src[0], vb = src[1];
    unsigned short h[8];
    h[0] = f32_to_bf16(va.x); h[1] = f32_to_bf16(va.y);
    h[2] = f32_to_bf16(va.z); h[3] = f32_to_bf16(va.w);
    h[4] = f32_to_bf16(vb.x); h[5] = f32_to_bf16(vb.y);
    h[6] = f32_to_bf16(vb.z); h[7] = f32_to_bf16(vb.w);
    float ss = 0.f;
    #pragma unroll
    for (int k = 0; k < 8; ++k) {
        float f = bf16_to_f32(h[k]);
        ss = fmaf(f, f, ss);
    }
    uint4 pk;
    pk.x = (uint32_t)h[0] | ((uint32_t)h[1] << 16);
    pk.y = (uint32_t)h[2] | ((uint32_t)h[3] << 16);
    pk.z = (uint32_t)h[4] | ((uint32_t)h[5] << 16);
    pk.w = (uint32_t)h[6] | ((uint32_t)h[7] << 16);
    *reinterpret_cast<uint4*>(Bp + (size_t)g * 2048 + c16 * 128 + r * 8) = pk;

    ss += __shfl_xor(ss, 1);
    ss += __shfl_xor(ss, 2);
    ss += __shfl_xor(ss, 4);
    ss += __shfl_xor(ss, 8);
    if (c16 == 0) {
        float sig = sigma[0];
        float q = 0.7213475204444817f / (sig * sig);  // log2(e)/(2 sigma^2)
        cw[R] = make_float2(ss * q, alpha[R]);
    }
}

// Fused: blocks [0,nA) = preds + loss-sum; blocks [nA,nA+nMt) = K_MM regularizer.
// 512 threads = 8 waves in a 4(row)x2(col) grid; each wave owns 32 rows x 32
// cols of the 128x64 tile. Structure = R2 (76us): double-buffered 16KB DMA
// tiles, one __syncthreads per iteration, compiler-scheduled loop body.
// (R3 lesson: counted-vmcnt + sched_barrier(0) pins defeated the compiler's
// cross-iteration scheduling -- VGPR 60->44, +52us pure stall. Do not pin.)
//
// R4 change: registers, not pipelining. rocprof VGPR_Count is ARCH regs only
// (R1: forced 64-budget compiled to 32 arch + 32 acc); R2 = 60 arch + 8 acc
// (2x f32x4 MFMA accumulators) = 68 > 64 -> 7 waves/SIMD -> 3 blocks/CU ->
// 768 slots < 798 blocks -> second-round straggler tail (Occupancy 58%).
// Fix: eliminate rowterm[2][4] (8 arch regs) by folding the row term into
// the MFMA C-operand: rtl[row] = -||x_row||^2/2 in LDS (exact: rowterm/q2 =
// ss/2, a power-of-2 divide); each iteration inits acc via ds_read_b128 of
// rtl (16-lane-uniform address -> broadcast). Then u = fmaf(acc,q2,-cj.x):
// also kills the per-output rowterm+cj.x add (epilogue 4 -> 3 VALU/output).
// Target: <=56 arch + 8 acc = 64 -> 8 waves/SIMD -> 4 blocks/CU, whole grid
// co-resident.
__global__ __launch_bounds__(512, 4)
void fused_kernel(const float* __restrict__ X, int N,
                  const float* __restrict__ Yv,
                  const unsigned short* __restrict__ Bp,
                  const float2* __restrict__ cw,
                  const float* __restrict__ alpha,
                  const float* __restrict__ sigma,
                  const float* __restrict__ penalty,
                  int nA, int nMt, int nBlk,
                  float* __restrict__ preds_out,
                  float* __restrict__ out0,
                  float* __restrict__ acc)   // [0]=loss,[1]=reg,[2]=counter
{
    // ldsB[0] doubles as the A-staging buffer before the m-loop starts.
    __shared__ __align__(16) unsigned short ldsB[2][8192];  // 2 x 16 KB
    __shared__ float a2p[TILE][4];
    __shared__ float predbuf[TILE][2];
    __shared__ __align__(16) float rtl[TILE];   // -||row||^2 / 2 (acc C-init)

    const int t    = threadIdx.x;
    const int lane = t & 63;
    const int wid  = t >> 6;     // 0..7
    const int wr   = wid >> 1;   // 0..3: rows wr*32 .. +32
    const int wc   = wid & 1;    // 0..1: cols wc*32 .. +32
    const int l15  = lane & 15;
    const int quad = lane >> 4;

    const float sig = sigma[0];
    const float q  = 0.7213475204444817f / (sig * sig);
    const float q2 = 2.0f * q;

    const bool regmode = (int)blockIdx.x >= nA;
    int rowbase;
    short8 a[8];   // A fragments, tile-invariant: a[i*4+kk], i in {0,1}

    if (!regmode) {
        rowbase = blockIdx.x * TILE;
        // stage X tile into fragment-layout LDS (whole 32KB of ldsB);
        // each thread converts a quarter-row (32 elems)
        const int r_  = t >> 2;
        const int qtr = t & 3;
        const int grow = rowbase + r_;
        unsigned short* dstbase = &ldsB[0][0] + (r_ >> 4) * 2048 + (r_ & 15) * 8;
        float ss = 0.f;
        if (grow < N) {
            const float4* src = (const float4*)(X + (size_t)grow * 128 + qtr * 32);
            #pragma unroll
            for (int c = 0; c < 4; ++c) {
                float4 va = src[2 * c], vb = src[2 * c + 1];
                unsigned short h0 = f32_to_bf16(va.x), h1 = f32_to_bf16(va.y);
                unsigned short h2 = f32_to_bf16(va.z), h3 = f32_to_bf16(va.w);
                unsigned short h4 = f32_to_bf16(vb.x), h5 = f32_to_bf16(vb.y);
                unsigned short h6 = f32_to_bf16(vb.z), h7 = f32_to_bf16(vb.w);
                float f0 = bf16_to_f32(h0), f1 = bf16_to_f32(h1);
                float f2 = bf16_to_f32(h2), f3 = bf16_to_f32(h3);
                float f4 = bf16_to_f32(h4), f5 = bf16_to_f32(h5);
                float f6 = bf16_to_f32(h6), f7 = bf16_to_f32(h7);
                ss = fmaf(f0, f0, ss); ss = fmaf(f1, f1, ss);
                ss = fmaf(f2, f2, ss); ss = fmaf(f3, f3, ss);
                ss = fmaf(f4, f4, ss); ss = fmaf(f5, f5, ss);
                ss = fmaf(f6, f6, ss); ss = fmaf(f7, f7, ss);
                uint4 pk;
                pk.x = (uint32_t)h0 | ((uint32_t)h1 << 16);
                pk.y = (uint32_t)h2 | ((uint32_t)h3 << 16);
                pk.z = (uint32_t)h4 | ((uint32_t)h5 << 16);
                pk.w = (uint32_t)h6 | ((uint32_t)h7 << 16);
                *reinterpret_cast<uint4*>(dstbase + (qtr * 4 + c) * 128) = pk;
            }
        } else {
            uint4 z; z.x = z.y = z.z = z.w = 0u;
            #pragma unroll
            for (int c = 0; c < 4; ++c)
                *reinterpret_cast<uint4*>(dstbase + (qtr * 4 + c) * 128) = z;
        }
        a2p[r_][qtr] = ss;
        __syncthreads();
        if (t < TILE)
            rtl[t] = -0.5f * (a2p[t][0] + a2p[t][1] + a2p[t][2] + a2p[t][3]);
        // hoist A fragments: 8 ds_read_b128, once for the whole kernel
        const unsigned short* aLds = &ldsB[0][0] + (size_t)(wr * 2) * 2048 + lane * 8;
        #pragma unroll
        for (int i = 0; i < 2; ++i)
            #pragma unroll
            for (int kk = 0; kk < 4; ++kk)
                a[i * 4 + kk] = *reinterpret_cast<const short8*>(aLds + (size_t)i * 2048 + kk * 512);
        __syncthreads();   // all waves done reading A from ldsB before DMA overwrites
    } else {
        const int b2 = (int)blockIdx.x - nA;
        rowbase = b2 * TILE;
        const unsigned short* aG = Bp + (size_t)(b2 * 8 + wr * 2) * 2048 + lane * 8;
        #pragma unroll
        for (int i = 0; i < 2; ++i)
            #pragma unroll
            for (int kk = 0; kk < 4; ++kk)
                a[i * 4 + kk] = *reinterpret_cast<const short8*>(aG + (size_t)i * 2048 + kk * 512);
        const float inv_q2 = 0.5f / q;
        if (t < TILE)
            rtl[t] = -cw[rowbase + t].x * inv_q2;   // = -||c_row||^2/2 (up to 1 ulp)
        // rtl visible after the tile-0 __syncthreads below
    }

    float srow[2][4] = {};
    const float2* cwb = cw + wc * 32 + l15;
    const float* rtlp = &rtl[wr * 32 + quad * 4];   // i*16 applied at read

    // this wave stages its 2 KB eighth of each 16KB tile: 2 x 1KB DMA issues
    const int ldq = wid * 1024 + lane * 8;   // element offset (shorts)

    // DMA tile 0 into ldsB[0]
    {
        const unsigned short* g = Bp + ldq;
        unsigned short* l = &ldsB[0][0] + ldq;
        #pragma unroll
        for (int k = 0; k < 2; ++k)
            dma16(g + k * 512, l + k * 512);
    }
    __syncthreads();   // vmcnt drain: tile 0 resident (and rtl visible)

    for (int mt = 0; mt < nMt; ++mt) {
        if (mt + 1 < nMt) {
            // fire-and-forget DMA of tile mt+1 into the other buffer;
            // drained by the barrier at the END of this iteration.
            const unsigned short* g = Bp + (size_t)(mt + 1) * 8192 + ldq;
            unsigned short* l = &ldsB[(mt + 1) & 1][0] + ldq;
            #pragma unroll
            for (int k = 0; k < 2; ++k)
                dma16(g + k * 512, l + k * 512);
        }

        // column constants for this tile (L2-hot; latency covered by TLP)
        float2 cj[2];
        #pragma unroll
        for (int j = 0; j < 2; ++j) cj[j] = cwb[(size_t)mt * 64 + j * 16];

        // compute tile mt from LDS: 2 column groups of 16, K=128 each
        const unsigned short* bfr = &ldsB[mt & 1][0] + (size_t)(wc * 2) * 2048 + lane * 8;
        #pragma unroll
        for (int j = 0; j < 2; ++j) {
            short8 b[4];
            #pragma unroll
            for (int kk = 0; kk < 4; ++kk)
                b[kk] = *reinterpret_cast<const short8*>(bfr + (size_t)j * 2048 + kk * 512);

            // C-init = -||row||^2/2 from LDS (broadcast read, re-loaded per
            // iteration so the values don't occupy 8 regs across the loop)
            f32x4 acc4[2];
            acc4[0] = *reinterpret_cast<const f32x4*>(rtlp);
            acc4[1] = *reinterpret_cast<const f32x4*>(rtlp + 16);
            #pragma unroll
            for (int kk = 0; kk < 4; ++kk)
                #pragma unroll
                for (int i = 0; i < 2; ++i)
                    acc4[i] = __builtin_amdgcn_mfma_f32_16x16x32_bf16(
                        a[i * 4 + kk], b[kk], acc4[i], 0, 0, 0);

            // epilogue: u = q2*(dot - ||x||^2/2) - q*||c||^2 <= ~0
            #pragma unroll
            for (int i = 0; i < 2; ++i) {
                #pragma unroll
                for (int r = 0; r < 4; ++r) {
                    float u = fmaf(acc4[i][r], q2, -cj[j].x);
                    float e = __builtin_amdgcn_exp2f(u);
                    srow[i][r] = fmaf(e, cj[j].y, srow[i][r]);
                }
            }
        }

        __syncthreads();   // drains DMA(mt+1); all waves done reading buf[mt&1]
    }

    // reduce srow over the 16 lanes sharing a row
    #pragma unroll
    for (int i = 0; i < 2; ++i) {
        #pragma unroll
        for (int r = 0; r < 4; ++r) {
            int rl = wr * 32 + i * 16 + quad * 4 + r;
            float v = srow[i][r];
            v += __shfl_xor(v, 1);
            v += __shfl_xor(v, 2);
            v += __shfl_xor(v, 4);
            v += __shfl_xor(v, 8);
            if (l15 == 0)
                predbuf[rl][wc] = v;
        }
    }
    __syncthreads();

    float contrib = 0.f;
    if (t < TILE) {
        int grow = rowbase + t;
        if (!regmode) {
            if (grow < N) {
                float pred = predbuf[t][0] + predbuf[t][1];
                preds_out[grow] = pred;
                float d = pred - Yv[grow];
                contrib = d * d;
            }
        } else {
            float pred = predbuf[t][0] + predbuf[t][1];
            contrib = alpha[grow] * pred;
        }
    }
    contrib += __shfl_xor(contrib, 1);
    contrib += __shfl_xor(contrib, 2);
    contrib += __shfl_xor(contrib, 4);
    contrib += __shfl_xor(contrib, 8);
    contrib += __shfl_xor(contrib, 16);
    contrib += __shfl_xor(contrib, 32);
    if (lane == 0 && wid < 2) atomicAdd(regmode ? (acc + 1) : (acc + 0), contrib);

    __syncthreads();   // all waves' atomics drained before counting
    if (t == 0) {
        __threadfence();
        unsigned int old = atomicAdd((unsigned int*)(acc + 2), 1u);
        if (old == (unsigned int)(nBlk - 1)) {
            float lv = atomicAdd(acc + 0, 0.0f);   // coherent read-back
            float rv = atomicAdd(acc + 1, 0.0f);
            out0[0] = lv / (float)N + __expf(-penalty[0]) * rv;
        }
    }
}

extern "C" void kernel_launch(void* const* d_in, const int* in_sizes, int n_in,
                              void* d_out, int out_size, void* d_ws, size_t ws_size,
                              hipStream_t stream) {
    const float* X       = (const float*)d_in[0];
    const float* Y       = (const float*)d_in[1];
    const float* centers = (const float*)d_in[2];
    const float* alpha   = (const float*)d_in[3];
    const float* sigma   = (const float*)d_in[4];
    const float* penalty = (const float*)d_in[5];
    float* out = (float*)d_out;

    const int N = in_sizes[1];   // Y is [N,1]
    const int M = in_sizes[3];   // alpha is [M,1]

    unsigned short* Bp = (unsigned short*)d_ws;                 // M*128 bf16 = M*256 B
    float2* cw = (float2*)((char*)d_ws + (size_t)M * 256);      // M*8 B
    float* acc = (float*)((char*)d_ws + (size_t)M * 264);       // loss, reg, counter

    prep_kernel<<<M / 16, 256, 0, stream>>>(centers, alpha, sigma, Bp, cw, acc);

    const int nA  = (N + TILE - 1) / TILE;
    const int nMt = M / BCOLS;            // 64-col B tiles
    const int nBlk = nA + M / TILE;
    fused_kernel<<<nBlk, 512, 0, stream>>>(X, N, Y, Bp, cw, alpha, sigma, penalty,
                                           nA, nMt, nBlk, out + 1, out, acc);
}